// Round 6
// baseline (275.042 us; speedup 1.0000x reference)
//
#include <hip/hip_runtime.h>
#include <hip/hip_bf16.h>
#include <stdint.h>

#define ALPHA_LO 0.8187307530779818f
#define ALPHA_HI 0.9607894391523232f

#define BATCH 64
#define TT    2000
#define II    512
#define HH    512
#define MM    (BATCH*TT)
#define LCH   50
#define CCH   (TT/LCH)

typedef __bf16 bf16;
typedef bf16  bf16x8 __attribute__((ext_vector_type(8)));
typedef float f32x4  __attribute__((ext_vector_type(4)));

// ---------------- K0: convert + transpose W -> fragment-ordered bf16 image --
// Wbt[ks:16][jj:32][kq:4][fr:16][e:8]  = W[jj*16+fr][ks*32+kq*8+e]
// A wave reading frag j at lane offset lane*8 gets exactly the MFMA B-operand.
__global__ void k_convW(const float* __restrict__ W, bf16* __restrict__ Wbt) {
    const int t  = blockIdx.x * 256 + threadIdx.x;   // 0..32767
    const int h  = t >> 6;                           // 0..511 (B column)
    const int kb = t & 63;                           // 8-float k group
    const float* src = W + (size_t)h * II + kb * 8;
    float4 v0 = *(const float4*)(src);
    float4 v1 = *(const float4*)(src + 4);
    bf16x8 o;
    o[0]=(bf16)v0.x; o[1]=(bf16)v0.y; o[2]=(bf16)v0.z; o[3]=(bf16)v0.w;
    o[4]=(bf16)v1.x; o[5]=(bf16)v1.y; o[6]=(bf16)v1.z; o[7]=(bf16)v1.w;
    const int ks = kb >> 2, kq = kb & 3, jj = h >> 4, fr = h & 15;
    bf16* dst = Wbt + (size_t)ks * 16384 + jj * 512 + kq * 128 + fr * 8;
    *(bf16x8*)dst = o;
}

// ---------------- K1: GEMM  Y[M,H] = X[M,I] * W[H,I]^T  (bf16 MFMA) --------
// ZERO-SYNC variant: no LDS, no barriers, no waitcnt drains. Block 128x256,
// 4 waves (2m x 2n), wave tile 64x128, acc 4x8 frags. B frags load directly
// from the fragment-ordered Wbt image (wave-contiguous 1KB, L2-resident);
// A frags load directly from X (f32, 2x dwordx4/frag, imm-folded K offsets),
// double-buffered in regs, cvt to bf16 at step start. Compiler inserts only
// fine-grained per-register vmcnt; waves are fully independent.
__global__ __launch_bounds__(256, 2) void k_gemm(const float* __restrict__ X,
                                                 const bf16* __restrict__ Wbt,
                                                 bf16* __restrict__ Y) {
    const int tid  = threadIdx.x;
    // bijective XCD swizzle (2000 % 8 == 0): XCD k gets a contiguous m-range;
    // the nt=0/1 blocks of one m-tile are adjacent -> share X via L2.
    const int swz  = (blockIdx.x & 7) * 250 + (blockIdx.x >> 3);
    const int m0   = (swz >> 1) * 128;
    const int nt   = swz & 1;
    const int lane = tid & 63;
    const int wv   = tid >> 6;
    const int wm   = wv >> 1;            // m half (0..1)
    const int wn   = wv & 1;             // n half (0..1)
    const int fr   = lane & 15;
    const int kq   = lane >> 4;

    f32x4 acc[4][8] = {};

    // A bases: frag i -> rows m0 + wm*64 + i*16 + fr, k-offset kq*8.
    // All 16 K-steps reachable via immediate offsets (ks*128B <= 1920B).
    const float* abase[4];
    #pragma unroll
    for (int i = 0; i < 4; ++i)
        abase[i] = X + (size_t)(m0 + wm * 64 + i * 16 + fr) * II + kq * 8;

    // B base: frag j at bbase + ks*16384 + j*512 elements (j*1KB imm-foldable)
    const bf16* bbase = Wbt + (size_t)(nt * 16 + wn * 8) * 512 + lane * 8;

    float4 avb[2][4][2];
    // prologue: A(0)
    #pragma unroll
    for (int i = 0; i < 4; ++i) {
        avb[0][i][0] = *(const float4*)(abase[i]);
        avb[0][i][1] = *(const float4*)(abase[i] + 4);
    }

    #pragma unroll
    for (int ks = 0; ks < 16; ++ks) {
        // issue B(ks): 8 wave-contiguous 1KB loads from L2-resident image
        bf16x8 bb[8];
        #pragma unroll
        for (int j = 0; j < 8; ++j)
            bb[j] = *(const bf16x8*)(bbase + (size_t)ks * 16384 + j * 512);
        // cvt A(ks) f32 -> bf16 (waits only on A loads issued last step)
        bf16x8 af[4];
        #pragma unroll
        for (int i = 0; i < 4; ++i) {
            float4 a0 = avb[ks & 1][i][0], a1 = avb[ks & 1][i][1];
            af[i][0]=(bf16)a0.x; af[i][1]=(bf16)a0.y; af[i][2]=(bf16)a0.z; af[i][3]=(bf16)a0.w;
            af[i][4]=(bf16)a1.x; af[i][5]=(bf16)a1.y; af[i][6]=(bf16)a1.z; af[i][7]=(bf16)a1.w;
        }
        // issue A(ks+1) into the freed buffer
        if (ks < 15) {
            #pragma unroll
            for (int i = 0; i < 4; ++i) {
                avb[(ks + 1) & 1][i][0] = *(const float4*)(abase[i] + (ks + 1) * 32);
                avb[(ks + 1) & 1][i][1] = *(const float4*)(abase[i] + (ks + 1) * 32 + 4);
            }
        }
        // MFMA cluster (per-register vmcnt lets bb[0] start the chain early)
        __builtin_amdgcn_s_setprio(1);
        #pragma unroll
        for (int i = 0; i < 4; ++i)
            #pragma unroll
            for (int j = 0; j < 8; ++j)
                acc[i][j] = __builtin_amdgcn_mfma_f32_16x16x32_bf16(af[i], bb[j], acc[i][j], 0, 0, 0);
        __builtin_amdgcn_s_setprio(0);
    }

    // epilogue: C row = (lane>>4)*4 + r, col = lane&15
    #pragma unroll
    for (int i = 0; i < 4; ++i)
        #pragma unroll
        for (int j = 0; j < 8; ++j) {
            const int row = m0 + wm * 64 + i * 16 + kq * 4;
            const int col = nt * 256 + (wn * 8 + j) * 16 + fr;
            #pragma unroll
            for (int r = 0; r < 4; ++r)
                Y[(size_t)(row + r) * HH + col] = (bf16)acc[i][j][r];
        }
}

// ---------------- K2: per-chunk Horner partial ------------------------------
__global__ void k_chunk(const bf16* __restrict__ Y, const float* __restrict__ alpha,
                        float* __restrict__ P) {
    const int c = blockIdx.x, b = blockIdx.y;
    const int lane = threadIdx.x;
    const int h0 = lane * 8;
    float a[8], p[8];
    #pragma unroll
    for (int k = 0; k < 8; ++k) {
        a[k] = fminf(fmaxf(alpha[h0 + k], ALPHA_LO), ALPHA_HI);
        p[k] = 0.f;
    }
    const bf16* base = Y + ((size_t)b * TT + (size_t)c * LCH) * HH + h0;
    for (int j = 0; j < LCH; ++j) {
        bf16x8 w = *(const bf16x8*)(base + (size_t)j * HH);
        #pragma unroll
        for (int k = 0; k < 8; ++k) p[k] = a[k] * p[k] + (float)w[k];
    }
    float* po = P + ((size_t)c * BATCH + b) * HH + h0;
    #pragma unroll
    for (int k = 0; k < 8; ++k) po[k] = (1.f - a[k]) * p[k];
}

// ---------------- K3: sequential prefix over chunks -------------------------
__global__ void k_prefix(const float* __restrict__ alpha, const float* __restrict__ u0,
                         const float* __restrict__ P, float* __restrict__ V) {
    const int g = blockIdx.x * 256 + threadIdx.x;
    const int h = g & (HH - 1);
    float a = fminf(fmaxf(alpha[h], ALPHA_LO), ALPHA_HI);
    float a2 = a * a, a4 = a2 * a2, a5 = a4 * a;
    float b2 = a5 * a5, b4 = b2 * b2, a25 = b4 * a5;
    float aL = a25 * a25;
    float v = u0[g];
    for (int c = 0; c < CCH; ++c) {
        const size_t idx = (size_t)c * (BATCH * HH) + g;
        V[idx] = v;
        v = aL * v + P[idx];
    }
}

// ---------------- K4: per-chunk softmax accumulate --------------------------
__global__ void k_soft(const bf16* __restrict__ Y, const float* __restrict__ alpha,
                       const float* __restrict__ V, float* __restrict__ OutP) {
    const int c = blockIdx.x, b = blockIdx.y;
    const int lane = threadIdx.x;
    const int h0 = lane * 8;
    float a[8], bt[8], u[8], o[8];
    #pragma unroll
    for (int k = 0; k < 8; ++k) {
        a[k]  = fminf(fmaxf(alpha[h0 + k], ALPHA_LO), ALPHA_HI);
        bt[k] = 1.f - a[k];
        o[k]  = 0.f;
    }
    const float* vb = V + ((size_t)c * BATCH + b) * HH + h0;
    #pragma unroll
    for (int k = 0; k < 8; ++k) u[k] = vb[k];
    const bf16* base = Y + ((size_t)b * TT + (size_t)c * LCH) * HH + h0;
    for (int j = 0; j < LCH; ++j) {
        bf16x8 w = *(const bf16x8*)(base + (size_t)j * HH);
        float e[8], s = 0.f;
        #pragma unroll
        for (int k = 0; k < 8; ++k) {
            u[k] = a[k] * u[k] + bt[k] * (float)w[k];
            e[k] = __expf(u[k]);
            s += e[k];
        }
        #pragma unroll
        for (int off = 32; off >= 1; off >>= 1) s += __shfl_xor(s, off, 64);
        const float inv = 1.f / s;
        #pragma unroll
        for (int k = 0; k < 8; ++k) o[k] += e[k] * inv;
    }
    float* po = OutP + ((size_t)c * BATCH + b) * HH + h0;
    #pragma unroll
    for (int k = 0; k < 8; ++k) po[k] = o[k];
}

// ---------------- K5: reduce chunk partials -> out --------------------------
__global__ void k_reduce(const float* __restrict__ OutP, float* __restrict__ out) {
    const int g = blockIdx.x * 256 + threadIdx.x;
    float s = 0.f;
    for (int c = 0; c < CCH; ++c) s += OutP[(size_t)c * (BATCH * HH) + g];
    out[g] = s;
}

extern "C" void kernel_launch(void* const* d_in, const int* in_sizes, int n_in,
                              void* d_out, int out_size, void* d_ws, size_t ws_size,
                              hipStream_t stream) {
    const float* x     = (const float*)d_in[0];
    const float* W     = (const float*)d_in[1];
    const float* alpha = (const float*)d_in[2];
    const float* u0    = (const float*)d_in[3];
    float* out = (float*)d_out;

    char* ws = (char*)d_ws;
    bf16* Wbt = (bf16*)ws;                                  //   0.5 MB
    bf16* Yx  = (bf16*)(ws + 524288);                       // 131.1 MB
    float* P  = (float*)(ws + 524288 + 131072000);
    float* V  = P + (size_t)CCH * BATCH * HH;
    float* OutP = V + (size_t)CCH * BATCH * HH;

    hipLaunchKernelGGL(k_convW,  dim3(128),          dim3(256), 0, stream, W, Wbt);
    hipLaunchKernelGGL(k_gemm,   dim3(2000),         dim3(256), 0, stream, x, Wbt, Yx);
    hipLaunchKernelGGL(k_chunk,  dim3(CCH, BATCH),   dim3(64),  0, stream, Yx, alpha, P);
    hipLaunchKernelGGL(k_prefix, dim3(BATCH*HH/256), dim3(256), 0, stream, alpha, u0, P, V);
    hipLaunchKernelGGL(k_soft,   dim3(CCH, BATCH),   dim3(64),  0, stream, Yx, alpha, V, OutP);
    hipLaunchKernelGGL(k_reduce, dim3(BATCH*HH/256), dim3(256), 0, stream, OutP, out);
}

// Round 7
// 210.966 us; speedup vs baseline: 1.3037x; 1.3037x over previous
//
#include <hip/hip_runtime.h>
#include <hip/hip_bf16.h>
#include <stdint.h>

#define ALPHA_LO 0.8187307530779818f
#define ALPHA_HI 0.9607894391523232f

#define BATCH 64
#define TT    2000
#define II    512
#define HH    512
#define MM    (BATCH*TT)
#define LCH   50
#define CCH   (TT/LCH)

typedef __bf16 bf16;
typedef bf16  bf16x8 __attribute__((ext_vector_type(8)));
typedef float f32x4  __attribute__((ext_vector_type(4)));

#define GLDS(src, dst) __builtin_amdgcn_global_load_lds( \
    (const __attribute__((address_space(1))) unsigned int*)(src), \
    (__attribute__((address_space(3))) unsigned int*)(dst), 16, 0, 0)

// ---------------- K0: convert + transpose W -> fragment-ordered bf16 image --
// Wbt[kt:8][nt:2][kh:2][jj:16][kq:4][fr:16][e:8] = W[nt*256+jj*16+fr][kt*64+kh*32+kq*8+e]
// Per (kt,nt) the 32 KB chunk IS the LDS B-image -> glds identity copy;
// every wave-level LDS access is contiguous 1KB -> zero bank conflicts.
__global__ void k_convW(const float* __restrict__ W, bf16* __restrict__ Wbt) {
    const int t  = blockIdx.x * 256 + threadIdx.x;   // 0..32767
    const int h  = t >> 6;                           // 0..511 (B column)
    const int kb = t & 63;                           // 8-float k group
    const float* src = W + (size_t)h * II + kb * 8;
    float4 v0 = *(const float4*)(src);
    float4 v1 = *(const float4*)(src + 4);
    bf16x8 o;
    o[0]=(bf16)v0.x; o[1]=(bf16)v0.y; o[2]=(bf16)v0.z; o[3]=(bf16)v0.w;
    o[4]=(bf16)v1.x; o[5]=(bf16)v1.y; o[6]=(bf16)v1.z; o[7]=(bf16)v1.w;
    const int kt = kb >> 3, kh = (kb >> 2) & 1, kq = kb & 3;
    const int nt = h >> 8, jj = (h >> 4) & 15, fr = h & 15;
    bf16* dst = Wbt + ((size_t)(kt * 2 + nt) * 16384) + kh * 8192 + jj * 512 + kq * 128 + fr * 8;
    *(bf16x8*)dst = o;
}

// ---------------- K1: GEMM  Y[M,H] = X[M,I] * W[H,I]^T  (bf16 MFMA) --------
// 256x256 tile, BK=64, 8 waves (2m x 4n), wave tile 128x64 (8x4 frags).
// 4 phases per K-tile: {4 A-frag ds_reads + one staging duty + 16 MFMA}.
// Staging: B via glds (depth-1, buf^1), A via regs->cvt->ds_write (depth-1,
// reg-issue depth-2). Boundary: lgkmcnt(0) + counted vmcnt(8) (retires the
// 4 oldest = next tile's B glds; A-reg loads stay in flight) + raw s_barrier.
__global__ __launch_bounds__(512, 2) void k_gemm(const float* __restrict__ X,
                                                 const bf16* __restrict__ Wbt,
                                                 bf16* __restrict__ Y) {
    __shared__ bf16 Al[2][16384];   // 2 x 32 KB
    __shared__ bf16 Bl[2][16384];   // 2 x 32 KB
    const int tid  = threadIdx.x;
    // bijective XCD swizzle (1000 % 8 == 0)
    const int swz  = (blockIdx.x & 7) * 125 + (blockIdx.x >> 3);
    const int m0   = (swz >> 1) * 256;
    const int nt   = swz & 1;
    const int lane = tid & 63;
    const int wv   = tid >> 6;
    const int wm   = wv >> 2;            // 0..1
    const int wn   = wv & 3;             // 0..3

    f32x4 acc[8][4] = {};

    // A staging decode: unit u = tid + s*512 -> (kh,blk,kq,fr)
    int urow[4], ukoff[4], uoff[4];
    #pragma unroll
    for (int s = 0; s < 4; ++s) {
        const int u  = tid + s * 512;
        const int kh = u >> 10, blk = (u >> 6) & 15, kq = (u >> 4) & 3, fr = u & 15;
        urow[s]  = blk * 16 + fr;
        ukoff[s] = kh * 32 + kq * 8;
        uoff[s]  = u * 8;
    }
    const bf16* bsrc = Wbt + (size_t)nt * 16384 + tid * 8;   // + kt*32768 + s*4096

    float4 apref[8];

    #define ISSUE_A(kt_) do {                                                   \
        _Pragma("unroll")                                                       \
        for (int s = 0; s < 4; ++s) {                                           \
            const float* p = X + (size_t)(m0 + urow[s]) * II + (kt_) * 64 + ukoff[s]; \
            apref[s * 2]     = *(const float4*)(p);                             \
            apref[s * 2 + 1] = *(const float4*)(p + 4);                         \
        } } while (0)

    #define CVT_A(buf_) do {                                                    \
        _Pragma("unroll")                                                       \
        for (int s = 0; s < 4; ++s) {                                           \
            float4 a0 = apref[s * 2], a1 = apref[s * 2 + 1];                    \
            bf16x8 c;                                                           \
            c[0]=(bf16)a0.x; c[1]=(bf16)a0.y; c[2]=(bf16)a0.z; c[3]=(bf16)a0.w; \
            c[4]=(bf16)a1.x; c[5]=(bf16)a1.y; c[6]=(bf16)a1.z; c[7]=(bf16)a1.w; \
            *(bf16x8*)(&Al[buf_][uoff[s]]) = c;                                 \
        } } while (0)

    #define GLDS_B(kt_, buf_) do {                                              \
        _Pragma("unroll")                                                       \
        for (int s = 0; s < 4; ++s)                                             \
            GLDS(bsrc + (size_t)(kt_) * 32768 + s * 4096,                       \
                 &Bl[buf_][s * 4096 + tid * 8]);                                \
        } while (0)

    // prologue: B(0) glds; A(0) regs; cvt A(0) (drains); A(1) regs; barrier
    GLDS_B(0, 0);
    ISSUE_A(0);
    CVT_A(0);
    ISSUE_A(1);
    asm volatile("s_waitcnt lgkmcnt(0)" ::: "memory");
    __builtin_amdgcn_s_barrier();

    #pragma unroll
    for (int t = 0; t < 8; ++t) {
        const int buf = t & 1;
        const bf16* Ab = Al[buf];
        const bf16* Bb = Bl[buf];
        // B fragments for the whole K-tile (8 x contiguous-1KB ds_read_b128)
        bf16x8 bb[4][2];
        #pragma unroll
        for (int j = 0; j < 4; ++j)
            #pragma unroll
            for (int kh = 0; kh < 2; ++kh)
                bb[j][kh] = *(const bf16x8*)(Bb + kh * 8192 + (wn * 4 + j) * 512 + lane * 8);
        // 4 phases: 2 m-frags each, staging duties spread across phases
        #pragma unroll
        for (int p = 0; p < 4; ++p) {
            bf16x8 af[2][2];
            #pragma unroll
            for (int ii = 0; ii < 2; ++ii)
                #pragma unroll
                for (int kh = 0; kh < 2; ++kh)
                    af[ii][kh] = *(const bf16x8*)(Ab + kh * 8192 + (wm * 8 + p * 2 + ii) * 512 + lane * 8);
            if (p == 0 && t < 7) GLDS_B(t + 1, buf ^ 1);
            if (p == 1 && t < 7) CVT_A(buf ^ 1);     // auto-wait on apref(t+1) only
            if (p == 2 && t < 6) ISSUE_A(t + 2);
            __builtin_amdgcn_s_setprio(1);
            #pragma unroll
            for (int ii = 0; ii < 2; ++ii)
                #pragma unroll
                for (int j = 0; j < 4; ++j)
                    #pragma unroll
                    for (int kh = 0; kh < 2; ++kh)
                        acc[p * 2 + ii][j] = __builtin_amdgcn_mfma_f32_16x16x32_bf16(
                            af[ii][kh], bb[j][kh], acc[p * 2 + ii][j], 0, 0, 0);
            __builtin_amdgcn_s_setprio(0);
        }
        // K-tile boundary: drain own LDS ops; retire next tile's B glds
        // (oldest 4 of 12 outstanding) but keep A-reg loads in flight.
        asm volatile("s_waitcnt lgkmcnt(0)" ::: "memory");
        if (t < 6)       asm volatile("s_waitcnt vmcnt(8)" ::: "memory");
        else if (t == 6) asm volatile("s_waitcnt vmcnt(0)" ::: "memory");
        if (t < 7) __builtin_amdgcn_s_barrier();
    }

    // epilogue: C row = (lane>>4)*4 + r, col = lane&15
    const int fr = lane & 15;
    const int kq = lane >> 4;
    #pragma unroll
    for (int i = 0; i < 8; ++i)
        #pragma unroll
        for (int j = 0; j < 4; ++j) {
            const int row = m0 + wm * 128 + i * 16 + kq * 4;
            const int col = nt * 256 + wn * 64 + j * 16 + fr;
            #pragma unroll
            for (int r = 0; r < 4; ++r)
                Y[(size_t)(row + r) * HH + col] = (bf16)acc[i][j][r];
        }
    #undef ISSUE_A
    #undef CVT_A
    #undef GLDS_B
}

// ---------------- K2: per-chunk Horner partial ------------------------------
__global__ void k_chunk(const bf16* __restrict__ Y, const float* __restrict__ alpha,
                        float* __restrict__ P) {
    const int c = blockIdx.x, b = blockIdx.y;
    const int lane = threadIdx.x;
    const int h0 = lane * 8;
    float a[8], p[8];
    #pragma unroll
    for (int k = 0; k < 8; ++k) {
        a[k] = fminf(fmaxf(alpha[h0 + k], ALPHA_LO), ALPHA_HI);
        p[k] = 0.f;
    }
    const bf16* base = Y + ((size_t)b * TT + (size_t)c * LCH) * HH + h0;
    for (int j = 0; j < LCH; ++j) {
        bf16x8 w = *(const bf16x8*)(base + (size_t)j * HH);
        #pragma unroll
        for (int k = 0; k < 8; ++k) p[k] = a[k] * p[k] + (float)w[k];
    }
    float* po = P + ((size_t)c * BATCH + b) * HH + h0;
    #pragma unroll
    for (int k = 0; k < 8; ++k) po[k] = (1.f - a[k]) * p[k];
}

// ---------------- K3: sequential prefix over chunks -------------------------
__global__ void k_prefix(const float* __restrict__ alpha, const float* __restrict__ u0,
                         const float* __restrict__ P, float* __restrict__ V) {
    const int g = blockIdx.x * 256 + threadIdx.x;
    const int h = g & (HH - 1);
    float a = fminf(fmaxf(alpha[h], ALPHA_LO), ALPHA_HI);
    float a2 = a * a, a4 = a2 * a2, a5 = a4 * a;
    float b2 = a5 * a5, b4 = b2 * b2, a25 = b4 * a5;
    float aL = a25 * a25;
    float v = u0[g];
    for (int c = 0; c < CCH; ++c) {
        const size_t idx = (size_t)c * (BATCH * HH) + g;
        V[idx] = v;
        v = aL * v + P[idx];
    }
}

// ---------------- K4: per-chunk softmax accumulate --------------------------
__global__ void k_soft(const bf16* __restrict__ Y, const float* __restrict__ alpha,
                       const float* __restrict__ V, float* __restrict__ OutP) {
    const int c = blockIdx.x, b = blockIdx.y;
    const int lane = threadIdx.x;
    const int h0 = lane * 8;
    float a[8], bt[8], u[8], o[8];
    #pragma unroll
    for (int k = 0; k < 8; ++k) {
        a[k]  = fminf(fmaxf(alpha[h0 + k], ALPHA_LO), ALPHA_HI);
        bt[k] = 1.f - a[k];
        o[k]  = 0.f;
    }
    const float* vb = V + ((size_t)c * BATCH + b) * HH + h0;
    #pragma unroll
    for (int k = 0; k < 8; ++k) u[k] = vb[k];
    const bf16* base = Y + ((size_t)b * TT + (size_t)c * LCH) * HH + h0;
    for (int j = 0; j < LCH; ++j) {
        bf16x8 w = *(const bf16x8*)(base + (size_t)j * HH);
        float e[8], s = 0.f;
        #pragma unroll
        for (int k = 0; k < 8; ++k) {
            u[k] = a[k] * u[k] + bt[k] * (float)w[k];
            e[k] = __expf(u[k]);
            s += e[k];
        }
        #pragma unroll
        for (int off = 32; off >= 1; off >>= 1) s += __shfl_xor(s, off, 64);
        const float inv = 1.f / s;
        #pragma unroll
        for (int k = 0; k < 8; ++k) o[k] += e[k] * inv;
    }
    float* po = OutP + ((size_t)c * BATCH + b) * HH + h0;
    #pragma unroll
    for (int k = 0; k < 8; ++k) po[k] = o[k];
}

// ---------------- K5: reduce chunk partials -> out --------------------------
__global__ void k_reduce(const float* __restrict__ OutP, float* __restrict__ out) {
    const int g = blockIdx.x * 256 + threadIdx.x;
    float s = 0.f;
    for (int c = 0; c < CCH; ++c) s += OutP[(size_t)c * (BATCH * HH) + g];
    out[g] = s;
}

extern "C" void kernel_launch(void* const* d_in, const int* in_sizes, int n_in,
                              void* d_out, int out_size, void* d_ws, size_t ws_size,
                              hipStream_t stream) {
    const float* x     = (const float*)d_in[0];
    const float* W     = (const float*)d_in[1];
    const float* alpha = (const float*)d_in[2];
    const float* u0    = (const float*)d_in[3];
    float* out = (float*)d_out;

    char* ws = (char*)d_ws;
    bf16* Wbt = (bf16*)ws;                                  //   0.5 MB
    bf16* Yx  = (bf16*)(ws + 524288);                       // 131.1 MB
    float* P  = (float*)(ws + 524288 + 131072000);
    float* V  = P + (size_t)CCH * BATCH * HH;
    float* OutP = V + (size_t)CCH * BATCH * HH;

    hipLaunchKernelGGL(k_convW,  dim3(128),          dim3(256), 0, stream, W, Wbt);
    hipLaunchKernelGGL(k_gemm,   dim3(1000),         dim3(512), 0, stream, x, Wbt, Yx);
    hipLaunchKernelGGL(k_chunk,  dim3(CCH, BATCH),   dim3(64),  0, stream, Yx, alpha, P);
    hipLaunchKernelGGL(k_prefix, dim3(BATCH*HH/256), dim3(256), 0, stream, alpha, u0, P, V);
    hipLaunchKernelGGL(k_soft,   dim3(CCH, BATCH),   dim3(64),  0, stream, Yx, alpha, V, OutP);
    hipLaunchKernelGGL(k_reduce, dim3(BATCH*HH/256), dim3(256), 0, stream, OutP, out);
}